// Round 1
// baseline (118.513 us; speedup 1.0000x reference)
//
#include <hip/hip_runtime.h>
#include <math.h>

#define NN 512
#define MM 100

// ws layout (floats):
//  St   [NN*MM]   sin table: St[x*MM + j] = sin(pi * x/(NN-1) * (j+1))
//  B_u  [MM*NN]   transposed: B_u[j*NN + x]
//  B_v  [MM*NN]
//  dx   [NN*NN]
//  dy   [NN*NN]

__global__ void sin_table_kernel(float* __restrict__ St) {
    int tid = blockIdx.x * blockDim.x + threadIdx.x;
    if (tid >= NN * MM) return;
    int x = tid / MM, j = tid % MM;
    // double-precision one-time table for accuracy vs np reference
    double arg = M_PI * ((double)x / (double)(NN - 1)) * (double)(j + 1);
    St[tid] = (float)sin(arg);
}

__global__ void bcoef_kernel(const float* __restrict__ St,
                             const float* __restrict__ c_u,
                             const float* __restrict__ c_v,
                             float* __restrict__ B_u,
                             float* __restrict__ B_v) {
    int x = blockIdx.x;      // [0, NN)
    int j = threadIdx.x;     // [0, MM)
    if (j >= MM) return;
    float au = 0.f, av = 0.f;
    for (int i = 0; i < MM; ++i) {
        int i1 = i + 1, j1 = j + 1;
        int r2i = i1 * i1 + j1 * j1;
        // e = (r < M+0.5) / r ; r2 <= 10100 <=> r < 100.5 (integer r2)
        float w = (r2i <= 10100) ? (1.0f / sqrtf((float)r2i)) : 0.0f;
        float sw = St[x * MM + i] * w;
        au += sw * c_u[i * MM + j];
        av += sw * c_v[i * MM + j];
    }
    B_u[j * NN + x] = au;   // transposed store -> coalesced reads later
    B_v[j * NN + x] = av;
}

__global__ void field_kernel(const float* __restrict__ St,
                             const float* __restrict__ B_u,
                             const float* __restrict__ B_v,
                             float scale,
                             float* __restrict__ dx,
                             float* __restrict__ dy) {
    int tid = blockIdx.x * blockDim.x + threadIdx.x;   // y*NN + x
    if (tid >= NN * NN) return;
    int y = tid / NN, x = tid % NN;
    float du = 0.f, dv = 0.f;
    #pragma unroll 4
    for (int j = 0; j < MM; ++j) {
        float s = St[y * MM + j];        // broadcast within block (same y)
        du += B_u[j * NN + x] * s;       // coalesced
        dv += B_v[j * NN + x] * s;
    }
    dx[tid] = scale * du;
    dy[tid] = scale * dv;
}

#define PLANES_PER_BLOCK 8

__global__ void remap_kernel(const float* __restrict__ img,
                             const float* __restrict__ dx,
                             const float* __restrict__ dy,
                             float* __restrict__ out,
                             int planes) {
    int tid = blockIdx.x * blockDim.x + threadIdx.x;   // over NN*NN
    if (tid >= NN * NN) return;
    int y = tid / NN, x = tid % NN;

    float xn = fminf(fmaxf((float)x - dx[tid], 0.0f), (float)(NN - 1));
    float yn = fminf(fmaxf((float)y - dy[tid], 0.0f), (float)(NN - 1));

    int xf = (int)floorf(xn), yf = (int)floorf(yn);
    int xc = (int)ceilf(xn),  yc = (int)ceilf(yn);
    float xv = xn - (float)xf, yv = yn - (float)yf;

    float w00 = (1.f - yv) * (1.f - xv);
    float w01 = (1.f - yv) * xv;
    float w10 = yv * (1.f - xv);
    float w11 = yv * xv;

    int i00 = yf * NN + xf, i01 = yf * NN + xc;
    int i10 = yc * NN + xf, i11 = yc * NN + xc;

    int p0 = blockIdx.y * PLANES_PER_BLOCK;
    int p1 = p0 + PLANES_PER_BLOCK; if (p1 > planes) p1 = planes;
    for (int p = p0; p < p1; ++p) {
        const float* ip = img + (size_t)p * (NN * NN);
        out[(size_t)p * (NN * NN) + tid] =
            w00 * ip[i00] + w01 * ip[i01] + w10 * ip[i10] + w11 * ip[i11];
    }
}

extern "C" void kernel_launch(void* const* d_in, const int* in_sizes, int n_in,
                              void* d_out, int out_size, void* d_ws, size_t ws_size,
                              hipStream_t stream) {
    const float* img = (const float*)d_in[0];
    const float* c_u = (const float*)d_in[1];
    const float* c_v = (const float*)d_in[2];
    float* out = (float*)d_out;

    int planes = in_sizes[0] / (NN * NN);   // 96

    float* ws  = (float*)d_ws;
    float* St  = ws;
    float* B_u = St  + NN * MM;
    float* B_v = B_u + MM * NN;
    float* dx  = B_v + MM * NN;
    float* dy  = dx  + NN * NN;

    // T = midpoint of temperature_range(n, cut), computed host-side (pure math)
    double log_cut = log((double)MM + 1e-6);
    double T1 = 1.0 / (M_PI * (double)NN * (double)NN * log_cut);
    double T2 = 4.0 / (M_PI * M_PI * M_PI * (double)MM * (double)MM * log_cut);
    if (T2 < T1) T2 = T1;
    double T = 0.5 * (T1 + T2);
    float scale = (float)(sqrt(T) * (double)NN);

    sin_table_kernel<<<(NN * MM + 255) / 256, 256, 0, stream>>>(St);
    bcoef_kernel<<<NN, 128, 0, stream>>>(St, c_u, c_v, B_u, B_v);
    field_kernel<<<(NN * NN + 255) / 256, 256, 0, stream>>>(St, B_u, B_v, scale, dx, dy);

    dim3 grid((NN * NN + 255) / 256, (planes + PLANES_PER_BLOCK - 1) / PLANES_PER_BLOCK);
    remap_kernel<<<grid, 256, 0, stream>>>(img, dx, dy, out, planes);
}